// Round 9
// baseline (578.191 us; speedup 1.0000x reference)
//
#include <hip/hip_runtime.h>
#include <math.h>

#define NH   16
#define HD   64
#define HIDN 1024
#define NB   2
#define SEQ  2048
#define ROWS (NB*SEQ)   // 4096
#define BH   (NB*NH)    // 32

typedef __attribute__((ext_vector_type(8))) short bf16x8;
typedef __attribute__((ext_vector_type(8))) _Float16 f16x8;
typedef __attribute__((ext_vector_type(4))) float f32x4;
typedef _Float16 f16;

__device__ __forceinline__ unsigned short f2bf(float f) {
    unsigned u = __float_as_uint(f);
    u += 0x7FFF + ((u >> 16) & 1);          // RNE
    return (unsigned short)(u >> 16);
}
__device__ __forceinline__ bf16x8 ldfrag(const unsigned short* p) {
    return *(const bf16x8*)p;
}
__device__ __forceinline__ f16x8 ldfragh(const f16* p) {
    return *(const f16x8*)p;
}
__device__ __forceinline__ f32x4 mfma16(bf16x8 a, bf16x8 b, f32x4 c) {
    return __builtin_amdgcn_mfma_f32_16x16x32_bf16(a, b, c, 0, 0, 0);
}
__device__ __forceinline__ f32x4 mfma16h(f16x8 a, f16x8 b, f32x4 c) {
    return __builtin_amdgcn_mfma_f32_16x16x32_f16(a, b, c, 0, 0, 0);
}

// log2(1 + acos(c)); acos(1-u) ~ sqrt(u)*Q(u), Q = sqrt(2)*P4(u)
__device__ __forceinline__ float log2_1pacos(float c) {
    float u = fmaxf(1.0f - c, 0.0f);
    float s = __builtin_amdgcn_sqrtf(u);
    float p = fmaf(u, 2.68532e-3f, 7.89259e-3f);
    p = fmaf(u, p, 2.6516504e-2f);
    p = fmaf(u, p, 1.1785113e-1f);
    p = fmaf(u, p, 1.4142136f);
    return __builtin_amdgcn_logf(fmaf(s, p, 1.0f));   // log2(1+g)
}

// ---------------- f32 -> f16 convert (n % 8 == 0) ---------------------------
__global__ __launch_bounds__(256)
void conv_f16(const float* __restrict__ src, f16* __restrict__ dst) {
    int i = (blockIdx.x * 256 + threadIdx.x) * 8;
    float4 a = *(const float4*)(src + i);
    float4 b = *(const float4*)(src + i + 4);
    f16x8 o = { (f16)a.x, (f16)a.y, (f16)a.z, (f16)a.w,
                (f16)b.x, (f16)b.y, (f16)b.z, (f16)b.w };
    *(f16x8*)(dst + i) = o;
}

// -------- fp16 MFMA NT GEMM: C[M,N] = A[M,K]*B[N,K]^T + bias[N], C f32 ------
__global__ __launch_bounds__(256)
void gemm_nt_f16(const f16* __restrict__ A, const f16* __restrict__ B,
                 const float* __restrict__ bias, float* __restrict__ C,
                 int M, int N, int K)
{
    __shared__ f16 As[128 * 32];
    __shared__ f16 Bs[128 * 32];
    const int tid = threadIdx.x;
    const int lane = tid & 63, w = tid >> 6;
    const int ln = lane & 15, lq = lane >> 4;
    const int wm = (w >> 1) * 64, wn = (w & 1) * 64;
    const int m0 = blockIdx.x * 128, n0 = blockIdx.y * 128;

    const int srow = tid >> 1;
    const int scol = (tid & 1) * 16;
    const f16* Ag = A + (size_t)(m0 + srow) * K + scol;
    const f16* Bg = B + (size_t)(n0 + srow) * K + scol;
    f16* Asw = As + srow * 32 + scol;
    f16* Bsw = Bs + srow * 32 + scol;

    f32x4 acc[4][4];
    #pragma unroll
    for (int i = 0; i < 4; ++i)
        #pragma unroll
        for (int j = 0; j < 4; ++j) acc[i][j] = (f32x4){0.f, 0.f, 0.f, 0.f};

    for (int kc = 0; kc < K; kc += 32) {
        uint4 a0 = *(const uint4*)(Ag + kc);
        uint4 a1 = *(const uint4*)(Ag + kc + 8);
        uint4 b0 = *(const uint4*)(Bg + kc);
        uint4 b1 = *(const uint4*)(Bg + kc + 8);
        __syncthreads();
        *(uint4*)Asw = a0; *(uint4*)(Asw + 8) = a1;
        *(uint4*)Bsw = b0; *(uint4*)(Bsw + 8) = b1;
        __syncthreads();
        f16x8 af[4], bf[4];
        #pragma unroll
        for (int i = 0; i < 4; ++i)
            af[i] = *(const f16x8*)&As[(wm + i * 16 + ln) * 32 + lq * 8];
        #pragma unroll
        for (int j = 0; j < 4; ++j)
            bf[j] = *(const f16x8*)&Bs[(wn + j * 16 + ln) * 32 + lq * 8];
        #pragma unroll
        for (int i = 0; i < 4; ++i)
            #pragma unroll
            for (int j = 0; j < 4; ++j)
                acc[i][j] = mfma16h(af[i], bf[j], acc[i][j]);
    }

    #pragma unroll
    for (int i = 0; i < 4; ++i) {
        #pragma unroll
        for (int j = 0; j < 4; ++j) {
            int colIdx = n0 + wn + j * 16 + ln;
            float bs = bias[colIdx];
            #pragma unroll
            for (int r = 0; r < 4; ++r) {
                int row = m0 + wm + i * 16 + lq * 4 + r;
                C[(size_t)row * N + colIdx] = acc[i][j][r] + bs;
            }
        }
    }
}

// ------- normalize q,k -> f16; layout [BH][S][D] ----------------------------
__global__ __launch_bounds__(256)
void normalize_qk_f16(const float* __restrict__ qkv,
                      f16* __restrict__ qf, f16* __restrict__ kf)
{
    int w    = blockIdx.x * 4 + (threadIdx.x >> 6);
    int lane = threadIdx.x & 63;
    int n = w >> 4, h = w & 15;
    int b = n >> 11, s = n & 2047;
    const float* base = qkv + (size_t)n * 3 * HIDN + h * HD;
    float q = base[lane], k = base[HIDN + lane];
    float qs = q * q, ks = k * k;
    #pragma unroll
    for (int o = 32; o; o >>= 1) { qs += __shfl_xor(qs, o); ks += __shfl_xor(ks, o); }
    q *= 1.0f / fmaxf(sqrtf(qs), 1e-12f);
    k *= 1.0f / fmaxf(sqrtf(ks), 1e-12f);
    size_t idx = ((size_t)((b * NH + h) * SEQ + s)) * HD + lane;
    qf[idx] = (f16)q;
    kf[idx] = (f16)k;
}

// ------- V: bf16, transpose to [BH][D][S] -----------------------------------
__global__ __launch_bounds__(256)
void v_transpose(const float* __restrict__ qkv, unsigned short* __restrict__ vth)
{
    __shared__ float Ls[64][65];
    int bh = blockIdx.y, s0 = blockIdx.x * 64;
    int b = bh >> 4, h = bh & 15;
    int tid = threadIdx.x;
    #pragma unroll
    for (int i = 0; i < 4; ++i) {
        int idx = tid + i * 256;
        int row = idx >> 4, c4 = (idx & 15) * 4;
        float4 v = *(const float4*)&qkv[((size_t)(b * SEQ + s0 + row)) * 3 * HIDN
                                        + 2 * HIDN + h * HD + c4];
        Ls[row][c4+0] = v.x; Ls[row][c4+1] = v.y; Ls[row][c4+2] = v.z; Ls[row][c4+3] = v.w;
    }
    __syncthreads();
    int d = tid >> 2, sb = (tid & 3) * 16;
    unsigned short hi[16];
    #pragma unroll
    for (int j = 0; j < 16; ++j) hi[j] = f2bf(Ls[sb + j][d]);
    size_t o = ((size_t)bh * HD + d) * SEQ + s0 + sb;
    *(uint4*)&vth[o]     = *(uint4*)&hi[0];
    *(uint4*)&vth[o + 8] = *(uint4*)&hi[8];
}

#define KSTR 68

// ------- partial col sums over an s-half, Q staged in LDS (coalesced) -------
__global__ __launch_bounds__(256)
void col_sum_f16(const f16* __restrict__ qf, const f16* __restrict__ kf,
                 float* __restrict__ colp)
{
    __shared__ __align__(16) f16 Qs[64 * KSTR];
    int bh = blockIdx.y, z = blockIdx.z;
    int tid = threadIdx.x, w = tid >> 6, lane = tid & 63, ln = lane & 15, lq = lane >> 4;
    int m0 = blockIdx.x * 64 + w * 16;
    int s_base = z * (SEQ / 2);
    const f16* qb = qf + (size_t)bh * SEQ * HD;
    const int sr = tid >> 3;          // tile row 0..31
    const int sc = (tid & 7) * 8;     // f16 col offset

    size_t rowK = ((size_t)bh * SEQ + m0 + ln) * HD;
    f16x8 kf0 = ldfragh(kf + rowK + lq * 8), kf1 = ldfragh(kf + rowK + 32 + lq * 8);

    uint4 qa = *(const uint4*)(qb + (size_t)(s_base + sr) * HD + sc);
    uint4 qc = *(const uint4*)(qb + (size_t)(s_base + sr + 32) * HD + sc);

    float cacc[4] = {0.f, 0.f, 0.f, 0.f};
    #pragma unroll 1
    for (int st = 0; st < SEQ / 128; ++st) {
        __syncthreads();
        *(uint4*)&Qs[sr * KSTR + sc] = qa;
        *(uint4*)&Qs[(sr + 32) * KSTR + sc] = qc;
        int sn = s_base + ((st + 1 < SEQ / 128) ? (st + 1) * 64 : 0);
        qa = *(const uint4*)(qb + (size_t)(sn + sr) * HD + sc);
        qc = *(const uint4*)(qb + (size_t)(sn + sr + 32) * HD + sc);
        __syncthreads();
        #pragma unroll
        for (int nt = 0; nt < 4; ++nt) {
            const f16* qp = &Qs[(nt * 16 + ln) * KSTR + lq * 8];
            f32x4 sacc = {0.f, 0.f, 0.f, 0.f};
            sacc = mfma16h(kf0, *(const f16x8*)qp, sacc);
            sacc = mfma16h(kf1, *(const f16x8*)(qp + 32), sacc);
            #pragma unroll
            for (int r = 0; r < 4; ++r)
                cacc[r] += __builtin_amdgcn_exp2f(-65.0f * log2_1pacos(sacc[r]));
        }
    }
    #pragma unroll
    for (int r = 0; r < 4; ++r) {
        float v = cacc[r];
        v += __shfl_xor(v, 1); v += __shfl_xor(v, 2);
        v += __shfl_xor(v, 4); v += __shfl_xor(v, 8);
        if (ln == 0)
            colp[((size_t)z * BH + bh) * SEQ + m0 + lq * 4 + r] = v;
    }
}

// ------- col finalize: lcl = -0.5*log2(c0+c1) -------------------------------
__global__ __launch_bounds__(256)
void col_finalize(const float* __restrict__ colp, float* __restrict__ col)
{
    int i = (blockIdx.x * 256 + threadIdx.x) * 4;
    float4 a = *(const float4*)&colp[i];
    float4 b = *(const float4*)&colp[(size_t)BH * SEQ + i];
    float4 o;
    o.x = -0.5f * __builtin_amdgcn_logf(a.x + b.x);
    o.y = -0.5f * __builtin_amdgcn_logf(a.y + b.y);
    o.z = -0.5f * __builtin_amdgcn_logf(a.z + b.z);
    o.w = -0.5f * __builtin_amdgcn_logf(a.w + b.w);
    *(float4*)&col[i] = o;
}

// ------- attention partials over a t-half; K/V staged in LDS ----------------
// score: w = exp2(-65*log2(1+g) + lcl); den via ones-MFMA; W stored RTZ bf16
__global__ __launch_bounds__(256)
void attn_f16(const f16* __restrict__ qf, const f16* __restrict__ kf,
              const unsigned short* __restrict__ vth,
              const float* __restrict__ col,
              float* __restrict__ nump, float* __restrict__ denp)
{
    __shared__ __align__(16) f16 Ks[64 * KSTR];
    __shared__ __align__(16) unsigned short Vs[64 * KSTR];
    __shared__ __align__(16) unsigned short Ws[4][16 * KSTR];
    __shared__ float lcls[64];
    int bh = blockIdx.y, z = blockIdx.z;
    int tid = threadIdx.x, w = tid >> 6, lane = tid & 63, ln = lane & 15, lq = lane >> 4;
    int m0 = blockIdx.x * 64 + w * 16;
    int t_base = z * (SEQ / 2);
    unsigned short* ws = Ws[w];

    const f16* kb = kf + (size_t)bh * SEQ * HD;
    const unsigned short* vb = vth + (size_t)bh * HD * SEQ;
    const float* cb = col + (size_t)bh * SEQ;

    const int sr = tid >> 3;
    const int sc = (tid & 7) * 8;

    size_t rowQ = ((size_t)bh * SEQ + m0 + ln) * HD;
    f16x8 qf0 = ldfragh(qf + rowQ + lq * 8), qf1 = ldfragh(qf + rowQ + 32 + lq * 8);

    bf16x8 ones;
    #pragma unroll
    for (int i = 0; i < 8; ++i) ones[i] = (short)0x3F80;  // bf16 1.0

    f32x4 num[4];
    #pragma unroll
    for (int nt = 0; nt < 4; ++nt) num[nt] = (f32x4){0.f, 0.f, 0.f, 0.f};
    f32x4 den = {0.f, 0.f, 0.f, 0.f};

    uint4 ka = *(const uint4*)(kb + (size_t)(t_base + sr) * HD + sc);
    uint4 kc = *(const uint4*)(kb + (size_t)(t_base + sr + 32) * HD + sc);
    uint4 va = *(const uint4*)(vb + (size_t)sr * SEQ + t_base + sc);
    uint4 vc = *(const uint4*)(vb + (size_t)(sr + 32) * SEQ + t_base + sc);
    float clv = (tid < 64) ? cb[t_base + tid] : 0.f;

    #pragma unroll 1
    for (int tt = 0; tt < SEQ / 128; ++tt) {
        __syncthreads();
        *(uint4*)&Ks[sr * KSTR + sc] = ka;
        *(uint4*)&Ks[(sr + 32) * KSTR + sc] = kc;
        *(uint4*)&Vs[sr * KSTR + sc] = va;
        *(uint4*)&Vs[(sr + 32) * KSTR + sc] = vc;
        if (tid < 64) lcls[tid] = clv;
        int tn = t_base + ((tt + 1 < SEQ / 128) ? (tt + 1) * 64 : 0);
        ka = *(const uint4*)(kb + (size_t)(tn + sr) * HD + sc);
        kc = *(const uint4*)(kb + (size_t)(tn + sr + 32) * HD + sc);
        va = *(const uint4*)(vb + (size_t)sr * SEQ + tn + sc);
        vc = *(const uint4*)(vb + (size_t)(sr + 32) * SEQ + tn + sc);
        clv = (tid < 64) ? cb[tn + tid] : 0.f;
        __syncthreads();

        // QK^T + score -> Ws (per-wave, RTZ bf16)
        #pragma unroll
        for (int nt = 0; nt < 4; ++nt) {
            const f16* kp = &Ks[(nt * 16 + ln) * KSTR + lq * 8];
            f32x4 sacc = {0.f, 0.f, 0.f, 0.f};
            sacc = mfma16h(qf0, *(const f16x8*)kp, sacc);
            sacc = mfma16h(qf1, *(const f16x8*)(kp + 32), sacc);
            float lcl = lcls[nt * 16 + ln];
            #pragma unroll
            for (int r = 0; r < 4; ++r) {
                float l = log2_1pacos(sacc[r]);
                float wv = __builtin_amdgcn_exp2f(fmaf(l, -65.0f, lcl));
                ws[(lq * 4 + r) * KSTR + nt * 16 + ln] =
                    (unsigned short)(__float_as_uint(wv) >> 16);   // RTZ
            }
        }
        // W in A-layout; den += W @ ones; num += W @ V
        bf16x8 wa0 = ldfrag(ws + ln * KSTR + lq * 8);
        bf16x8 wa1 = ldfrag(ws + ln * KSTR + 32 + lq * 8);
        den = mfma16(wa0, ones, den);
        den = mfma16(wa1, ones, den);
        #pragma unroll
        for (int nt = 0; nt < 4; ++nt) {
            const unsigned short* vp = &Vs[(nt * 16 + ln) * KSTR + lq * 8];
            num[nt] = mfma16(wa0, *(const bf16x8*)vp, num[nt]);
            num[nt] = mfma16(wa1, *(const bf16x8*)(vp + 32), num[nt]);
        }
    }

    if (ln == 0) {
        #pragma unroll
        for (int r = 0; r < 4; ++r)
            denp[((size_t)z * BH + bh) * SEQ + m0 + lq * 4 + r] = den[r];
    }
    float* np = nump + (((size_t)z * BH + bh) * (SEQ / 64) + blockIdx.x) * 4096
                + (size_t)(w * 16) * 64;
    #pragma unroll
    for (int nt = 0; nt < 4; ++nt)
        #pragma unroll
        for (int r = 0; r < 4; ++r)
            np[(lq * 4 + r) * 64 + nt * 16 + ln] = num[nt][r];
}

// ------- combine halves: ctx = (p0+p1)/(d0+d1), f16 out ---------------------
__global__ __launch_bounds__(256)
void attn_combine(const float* __restrict__ nump, const float* __restrict__ denp,
                  f16* __restrict__ ctx)
{
    int sT = blockIdx.x, bh = blockIdx.y;
    int b = bh >> 4, h = bh & 15;
    int tid = threadIdx.x;
    int s_l = tid >> 2, dg = (tid & 3) * 16;
    const float* p0 = nump + (((size_t)bh) * (SEQ / 64) + sT) * 4096 + s_l * 64 + dg;
    const float* p1 = nump + (((size_t)BH + bh) * (SEQ / 64) + sT) * 4096 + s_l * 64 + dg;
    int s = sT * 64 + s_l;
    float den = denp[(size_t)bh * SEQ + s] + denp[((size_t)BH + bh) * SEQ + s];
    float inv = 1.0f / fmaxf(den, 1e-12f);
    f16 o[16];
    #pragma unroll
    for (int j4 = 0; j4 < 4; ++j4) {
        float4 a = *(const float4*)(p0 + j4 * 4);
        float4 c = *(const float4*)(p1 + j4 * 4);
        o[j4*4+0] = (f16)((a.x + c.x) * inv);
        o[j4*4+1] = (f16)((a.y + c.y) * inv);
        o[j4*4+2] = (f16)((a.z + c.z) * inv);
        o[j4*4+3] = (f16)((a.w + c.w) * inv);
    }
    f16* dst = ctx + ((size_t)(b * SEQ + s)) * HIDN + h * HD + dg;
    *(f16x8*)dst = *(f16x8*)&o[0];
    *(f16x8*)(dst + 8) = *(f16x8*)&o[8];
}

extern "C" void kernel_launch(void* const* d_in, const int* in_sizes, int n_in,
                              void* d_out, int out_size, void* d_ws, size_t ws_size,
                              hipStream_t stream) {
    const float* x      = (const float*)d_in[0];
    const float* qkv_w  = (const float*)d_in[1];
    const float* qkv_b  = (const float*)d_in[2];
    const float* out_w  = (const float*)d_in[3];
    const float* out_b  = (const float*)d_in[4];
    float* out = (float*)d_out;

    const size_t NTT = (size_t)BH * SEQ * HD;             // 4.19M
    float* qkv = (float*)d_ws;                            // 12.58M f32
    float* nump = qkv;                                    // aliases dead qkv
    float* denp = nump + (size_t)2 * BH * (SEQ/64) * 4096;
    float* colp = denp + (size_t)2 * BH * SEQ;
    float* col = qkv + (size_t)ROWS * 3 * HIDN;           // holds lcl
    f16* xh    = (f16*)(col + (size_t)BH * SEQ);
    f16* wqh   = xh + (size_t)ROWS * HIDN;
    f16* woh   = wqh + (size_t)3 * HIDN * HIDN;
    f16* ctxh  = woh + (size_t)HIDN * HIDN;
    f16* qfp   = ctxh + (size_t)ROWS * HIDN;
    f16* kfp   = qfp + NTT;
    unsigned short* vth = (unsigned short*)(kfp + NTT);

    conv_f16<<<ROWS*HIDN/2048, 256, 0, stream>>>(x, xh);
    conv_f16<<<3*HIDN*HIDN/2048, 256, 0, stream>>>(qkv_w, wqh);
    conv_f16<<<HIDN*HIDN/2048, 256, 0, stream>>>(out_w, woh);

    gemm_nt_f16<<<dim3(ROWS/128, 3*HIDN/128), 256, 0, stream>>>(
        xh, wqh, qkv_b, qkv, ROWS, 3*HIDN, HIDN);
    normalize_qk_f16<<<ROWS*NH/4, 256, 0, stream>>>(qkv, qfp, kfp);
    v_transpose<<<dim3(SEQ/64, BH), 256, 0, stream>>>(qkv, vth);
    col_sum_f16<<<dim3(SEQ/64, BH, 2), 256, 0, stream>>>(qfp, kfp, colp);
    col_finalize<<<BH*SEQ/1024, 256, 0, stream>>>(colp, col);
    attn_f16<<<dim3(SEQ/64, BH, 2), 256, 0, stream>>>(qfp, kfp, vth, col, nump, denp);
    attn_combine<<<dim3(SEQ/64, BH), 256, 0, stream>>>(nump, denp, ctxh);
    gemm_nt_f16<<<dim3(ROWS/128, HIDN/128), 256, 0, stream>>>(
        ctxh, woh, out_b, out, ROWS, HIDN, HIDN);
}

// Round 10
// 332.006 us; speedup vs baseline: 1.7415x; 1.7415x over previous
//
#include <hip/hip_runtime.h>
#include <math.h>

#define NH   16
#define HD   64
#define HIDN 1024
#define NB   2
#define SEQ  2048
#define ROWS (NB*SEQ)   // 4096
#define BH   (NB*NH)    // 32

typedef __attribute__((ext_vector_type(8))) short bf16x8;
typedef __attribute__((ext_vector_type(8))) _Float16 f16x8;
typedef __attribute__((ext_vector_type(4))) float f32x4;
typedef _Float16 f16;

__device__ __forceinline__ unsigned short f2bf(float f) {
    unsigned u = __float_as_uint(f);
    u += 0x7FFF + ((u >> 16) & 1);          // RNE
    return (unsigned short)(u >> 16);
}
__device__ __forceinline__ bf16x8 ldfrag(const unsigned short* p) {
    return *(const bf16x8*)p;
}
__device__ __forceinline__ f16x8 ldfragh(const f16* p) {
    return *(const f16x8*)p;
}
__device__ __forceinline__ f32x4 mfma16(bf16x8 a, bf16x8 b, f32x4 c) {
    return __builtin_amdgcn_mfma_f32_16x16x32_bf16(a, b, c, 0, 0, 0);
}
__device__ __forceinline__ f32x4 mfma16h(f16x8 a, f16x8 b, f32x4 c) {
    return __builtin_amdgcn_mfma_f32_16x16x32_f16(a, b, c, 0, 0, 0);
}

// log2(1 + acos(c)); acos(1-u) ~ sqrt(u)*Q(u), Q = sqrt(2)*P4(u)
__device__ __forceinline__ float log2_1pacos(float c) {
    float u = fmaxf(1.0f - c, 0.0f);
    float s = __builtin_amdgcn_sqrtf(u);
    float p = fmaf(u, 2.68532e-3f, 7.89259e-3f);
    p = fmaf(u, p, 2.6516504e-2f);
    p = fmaf(u, p, 1.1785113e-1f);
    p = fmaf(u, p, 1.4142136f);
    return __builtin_amdgcn_logf(fmaf(s, p, 1.0f));   // log2(1+g)
}

// ---------------- f32 -> f16 convert (n % 8 == 0) ---------------------------
__global__ __launch_bounds__(256)
void conv_f16(const float* __restrict__ src, f16* __restrict__ dst) {
    int i = (blockIdx.x * 256 + threadIdx.x) * 8;
    float4 a = *(const float4*)(src + i);
    float4 b = *(const float4*)(src + i + 4);
    f16x8 o = { (f16)a.x, (f16)a.y, (f16)a.z, (f16)a.w,
                (f16)b.x, (f16)b.y, (f16)b.z, (f16)b.w };
    *(f16x8*)(dst + i) = o;
}

// -------- fp16 MFMA NT GEMM: C[M,N] = A[M,K]*B[N,K]^T + bias[N], C f32 ------
__global__ __launch_bounds__(256)
void gemm_nt_f16(const f16* __restrict__ A, const f16* __restrict__ B,
                 const float* __restrict__ bias, float* __restrict__ C,
                 int M, int N, int K)
{
    __shared__ f16 As[128 * 32];
    __shared__ f16 Bs[128 * 32];
    const int tid = threadIdx.x;
    const int lane = tid & 63, w = tid >> 6;
    const int ln = lane & 15, lq = lane >> 4;
    const int wm = (w >> 1) * 64, wn = (w & 1) * 64;
    const int m0 = blockIdx.x * 128, n0 = blockIdx.y * 128;

    const int srow = tid >> 1;
    const int scol = (tid & 1) * 16;
    const f16* Ag = A + (size_t)(m0 + srow) * K + scol;
    const f16* Bg = B + (size_t)(n0 + srow) * K + scol;
    f16* Asw = As + srow * 32 + scol;
    f16* Bsw = Bs + srow * 32 + scol;

    f32x4 acc[4][4];
    #pragma unroll
    for (int i = 0; i < 4; ++i)
        #pragma unroll
        for (int j = 0; j < 4; ++j) acc[i][j] = (f32x4){0.f, 0.f, 0.f, 0.f};

    for (int kc = 0; kc < K; kc += 32) {
        uint4 a0 = *(const uint4*)(Ag + kc);
        uint4 a1 = *(const uint4*)(Ag + kc + 8);
        uint4 b0 = *(const uint4*)(Bg + kc);
        uint4 b1 = *(const uint4*)(Bg + kc + 8);
        __syncthreads();
        *(uint4*)Asw = a0; *(uint4*)(Asw + 8) = a1;
        *(uint4*)Bsw = b0; *(uint4*)(Bsw + 8) = b1;
        __syncthreads();
        f16x8 af[4], bf[4];
        #pragma unroll
        for (int i = 0; i < 4; ++i)
            af[i] = *(const f16x8*)&As[(wm + i * 16 + ln) * 32 + lq * 8];
        #pragma unroll
        for (int j = 0; j < 4; ++j)
            bf[j] = *(const f16x8*)&Bs[(wn + j * 16 + ln) * 32 + lq * 8];
        #pragma unroll
        for (int i = 0; i < 4; ++i)
            #pragma unroll
            for (int j = 0; j < 4; ++j)
                acc[i][j] = mfma16h(af[i], bf[j], acc[i][j]);
    }

    #pragma unroll
    for (int i = 0; i < 4; ++i) {
        #pragma unroll
        for (int j = 0; j < 4; ++j) {
            int colIdx = n0 + wn + j * 16 + ln;
            float bs = bias[colIdx];
            #pragma unroll
            for (int r = 0; r < 4; ++r) {
                int row = m0 + wm + i * 16 + lq * 4 + r;
                C[(size_t)row * N + colIdx] = acc[i][j][r] + bs;
            }
        }
    }
}

// ------- normalize q,k -> f16; layout [BH][S][D] ----------------------------
__global__ __launch_bounds__(256)
void normalize_qk_f16(const float* __restrict__ qkv,
                      f16* __restrict__ qf, f16* __restrict__ kf)
{
    int w    = blockIdx.x * 4 + (threadIdx.x >> 6);
    int lane = threadIdx.x & 63;
    int n = w >> 4, h = w & 15;
    int b = n >> 11, s = n & 2047;
    const float* base = qkv + (size_t)n * 3 * HIDN + h * HD;
    float q = base[lane], k = base[HIDN + lane];
    float qs = q * q, ks = k * k;
    #pragma unroll
    for (int o = 32; o; o >>= 1) { qs += __shfl_xor(qs, o); ks += __shfl_xor(ks, o); }
    q *= 1.0f / fmaxf(sqrtf(qs), 1e-12f);
    k *= 1.0f / fmaxf(sqrtf(ks), 1e-12f);
    size_t idx = ((size_t)((b * NH + h) * SEQ + s)) * HD + lane;
    qf[idx] = (f16)q;
    kf[idx] = (f16)k;
}

// ------- V: bf16, transpose to [BH][D][S] -----------------------------------
__global__ __launch_bounds__(256)
void v_transpose(const float* __restrict__ qkv, unsigned short* __restrict__ vth)
{
    __shared__ float Ls[64][65];
    int bh = blockIdx.y, s0 = blockIdx.x * 64;
    int b = bh >> 4, h = bh & 15;
    int tid = threadIdx.x;
    #pragma unroll
    for (int i = 0; i < 4; ++i) {
        int idx = tid + i * 256;
        int row = idx >> 4, c4 = (idx & 15) * 4;
        float4 v = *(const float4*)&qkv[((size_t)(b * SEQ + s0 + row)) * 3 * HIDN
                                        + 2 * HIDN + h * HD + c4];
        Ls[row][c4+0] = v.x; Ls[row][c4+1] = v.y; Ls[row][c4+2] = v.z; Ls[row][c4+3] = v.w;
    }
    __syncthreads();
    int d = tid >> 2, sb = (tid & 3) * 16;
    unsigned short hi[16];
    #pragma unroll
    for (int j = 0; j < 16; ++j) hi[j] = f2bf(Ls[sb + j][d]);
    size_t o = ((size_t)bh * HD + d) * SEQ + s0 + sb;
    *(uint4*)&vth[o]     = *(uint4*)&hi[0];
    *(uint4*)&vth[o + 8] = *(uint4*)&hi[8];
}

// KSTR=72 f16 -> 144 B row stride: 16B-aligned (b128-clean), 2-way bank
// aliasing only (free). 68 was 8B-aligned -> misaligned b128, 2.5x regression.
#define KSTR 72

// ------- partial col sums over an s-half, Q staged in LDS (coalesced) -------
__global__ __launch_bounds__(256)
void col_sum_f16(const f16* __restrict__ qf, const f16* __restrict__ kf,
                 float* __restrict__ colp)
{
    __shared__ __align__(16) f16 Qs[64 * KSTR];
    int bh = blockIdx.y, z = blockIdx.z;
    int tid = threadIdx.x, w = tid >> 6, lane = tid & 63, ln = lane & 15, lq = lane >> 4;
    int m0 = blockIdx.x * 64 + w * 16;
    int s_base = z * (SEQ / 2);
    const f16* qb = qf + (size_t)bh * SEQ * HD;
    const int sr = tid >> 3;          // tile row 0..31
    const int sc = (tid & 7) * 8;     // f16 col offset

    size_t rowK = ((size_t)bh * SEQ + m0 + ln) * HD;
    f16x8 kf0 = ldfragh(kf + rowK + lq * 8), kf1 = ldfragh(kf + rowK + 32 + lq * 8);

    uint4 qa = *(const uint4*)(qb + (size_t)(s_base + sr) * HD + sc);
    uint4 qc = *(const uint4*)(qb + (size_t)(s_base + sr + 32) * HD + sc);

    float cacc[4] = {0.f, 0.f, 0.f, 0.f};
    #pragma unroll 1
    for (int st = 0; st < SEQ / 128; ++st) {
        __syncthreads();
        *(uint4*)&Qs[sr * KSTR + sc] = qa;
        *(uint4*)&Qs[(sr + 32) * KSTR + sc] = qc;
        int sn = s_base + ((st + 1 < SEQ / 128) ? (st + 1) * 64 : 0);
        qa = *(const uint4*)(qb + (size_t)(sn + sr) * HD + sc);
        qc = *(const uint4*)(qb + (size_t)(sn + sr + 32) * HD + sc);
        __syncthreads();
        #pragma unroll
        for (int nt = 0; nt < 4; ++nt) {
            const f16* qp = &Qs[(nt * 16 + ln) * KSTR + lq * 8];
            f32x4 sacc = {0.f, 0.f, 0.f, 0.f};
            sacc = mfma16h(kf0, *(const f16x8*)qp, sacc);
            sacc = mfma16h(kf1, *(const f16x8*)(qp + 32), sacc);
            #pragma unroll
            for (int r = 0; r < 4; ++r)
                cacc[r] += __builtin_amdgcn_exp2f(-65.0f * log2_1pacos(sacc[r]));
        }
    }
    #pragma unroll
    for (int r = 0; r < 4; ++r) {
        float v = cacc[r];
        v += __shfl_xor(v, 1); v += __shfl_xor(v, 2);
        v += __shfl_xor(v, 4); v += __shfl_xor(v, 8);
        if (ln == 0)
            colp[((size_t)z * BH + bh) * SEQ + m0 + lq * 4 + r] = v;
    }
}

// ------- col finalize: lcl = -0.5*log2(c0+c1) -------------------------------
__global__ __launch_bounds__(256)
void col_finalize(const float* __restrict__ colp, float* __restrict__ col)
{
    int i = (blockIdx.x * 256 + threadIdx.x) * 4;
    float4 a = *(const float4*)&colp[i];
    float4 b = *(const float4*)&colp[(size_t)BH * SEQ + i];
    float4 o;
    o.x = -0.5f * __builtin_amdgcn_logf(a.x + b.x);
    o.y = -0.5f * __builtin_amdgcn_logf(a.y + b.y);
    o.z = -0.5f * __builtin_amdgcn_logf(a.z + b.z);
    o.w = -0.5f * __builtin_amdgcn_logf(a.w + b.w);
    *(float4*)&col[i] = o;
}

// ------- attention partials over a t-half; K/V staged in LDS ----------------
// score: w = exp2(-65*log2(1+g) + lcl); den via ones-MFMA; W stored RTZ bf16
__global__ __launch_bounds__(256)
void attn_f16(const f16* __restrict__ qf, const f16* __restrict__ kf,
              const unsigned short* __restrict__ vth,
              const float* __restrict__ col,
              float* __restrict__ nump, float* __restrict__ denp)
{
    __shared__ __align__(16) f16 Ks[64 * KSTR];
    __shared__ __align__(16) unsigned short Vs[64 * KSTR];
    __shared__ __align__(16) unsigned short Ws[4][16 * KSTR];
    __shared__ float lcls[64];
    int bh = blockIdx.y, z = blockIdx.z;
    int tid = threadIdx.x, w = tid >> 6, lane = tid & 63, ln = lane & 15, lq = lane >> 4;
    int m0 = blockIdx.x * 64 + w * 16;
    int t_base = z * (SEQ / 2);
    unsigned short* ws = Ws[w];

    const f16* kb = kf + (size_t)bh * SEQ * HD;
    const unsigned short* vb = vth + (size_t)bh * HD * SEQ;
    const float* cb = col + (size_t)bh * SEQ;

    const int sr = tid >> 3;
    const int sc = (tid & 7) * 8;

    size_t rowQ = ((size_t)bh * SEQ + m0 + ln) * HD;
    f16x8 qf0 = ldfragh(qf + rowQ + lq * 8), qf1 = ldfragh(qf + rowQ + 32 + lq * 8);

    bf16x8 ones;
    #pragma unroll
    for (int i = 0; i < 8; ++i) ones[i] = (short)0x3F80;  // bf16 1.0

    f32x4 num[4];
    #pragma unroll
    for (int nt = 0; nt < 4; ++nt) num[nt] = (f32x4){0.f, 0.f, 0.f, 0.f};
    f32x4 den = {0.f, 0.f, 0.f, 0.f};

    uint4 ka = *(const uint4*)(kb + (size_t)(t_base + sr) * HD + sc);
    uint4 kc = *(const uint4*)(kb + (size_t)(t_base + sr + 32) * HD + sc);
    uint4 va = *(const uint4*)(vb + (size_t)sr * SEQ + t_base + sc);
    uint4 vc = *(const uint4*)(vb + (size_t)(sr + 32) * SEQ + t_base + sc);
    float clv = (tid < 64) ? cb[t_base + tid] : 0.f;

    #pragma unroll 1
    for (int tt = 0; tt < SEQ / 128; ++tt) {
        __syncthreads();
        *(uint4*)&Ks[sr * KSTR + sc] = ka;
        *(uint4*)&Ks[(sr + 32) * KSTR + sc] = kc;
        *(uint4*)&Vs[sr * KSTR + sc] = va;
        *(uint4*)&Vs[(sr + 32) * KSTR + sc] = vc;
        if (tid < 64) lcls[tid] = clv;
        int tn = t_base + ((tt + 1 < SEQ / 128) ? (tt + 1) * 64 : 0);
        ka = *(const uint4*)(kb + (size_t)(tn + sr) * HD + sc);
        kc = *(const uint4*)(kb + (size_t)(tn + sr + 32) * HD + sc);
        va = *(const uint4*)(vb + (size_t)sr * SEQ + tn + sc);
        vc = *(const uint4*)(vb + (size_t)(sr + 32) * SEQ + tn + sc);
        clv = (tid < 64) ? cb[tn + tid] : 0.f;
        __syncthreads();

        // QK^T + score -> Ws (per-wave, RTZ bf16)
        #pragma unroll
        for (int nt = 0; nt < 4; ++nt) {
            const f16* kp = &Ks[(nt * 16 + ln) * KSTR + lq * 8];
            f32x4 sacc = {0.f, 0.f, 0.f, 0.f};
            sacc = mfma16h(qf0, *(const f16x8*)kp, sacc);
            sacc = mfma16h(qf1, *(const f16x8*)(kp + 32), sacc);
            float lcl = lcls[nt * 16 + ln];
            #pragma unroll
            for (int r = 0; r < 4; ++r) {
                float l = log2_1pacos(sacc[r]);
                float wv = __builtin_amdgcn_exp2f(fmaf(l, -65.0f, lcl));
                ws[(lq * 4 + r) * KSTR + nt * 16 + ln] =
                    (unsigned short)(__float_as_uint(wv) >> 16);   // RTZ
            }
        }
        // W in A-layout; den += W @ ones; num += W @ V
        bf16x8 wa0 = ldfrag(ws + ln * KSTR + lq * 8);
        bf16x8 wa1 = ldfrag(ws + ln * KSTR + 32 + lq * 8);
        den = mfma16(wa0, ones, den);
        den = mfma16(wa1, ones, den);
        #pragma unroll
        for (int nt = 0; nt < 4; ++nt) {
            const unsigned short* vp = &Vs[(nt * 16 + ln) * KSTR + lq * 8];
            num[nt] = mfma16(wa0, *(const bf16x8*)vp, num[nt]);
            num[nt] = mfma16(wa1, *(const bf16x8*)(vp + 32), num[nt]);
        }
    }

    if (ln == 0) {
        #pragma unroll
        for (int r = 0; r < 4; ++r)
            denp[((size_t)z * BH + bh) * SEQ + m0 + lq * 4 + r] = den[r];
    }
    float* np = nump + (((size_t)z * BH + bh) * (SEQ / 64) + blockIdx.x) * 4096
                + (size_t)(w * 16) * 64;
    #pragma unroll
    for (int nt = 0; nt < 4; ++nt)
        #pragma unroll
        for (int r = 0; r < 4; ++r)
            np[(lq * 4 + r) * 64 + nt * 16 + ln] = num[nt][r];
}

// ------- combine halves: ctx = (p0+p1)/(d0+d1), f16 out ---------------------
__global__ __launch_bounds__(256)
void attn_combine(const float* __restrict__ nump, const float* __restrict__ denp,
                  f16* __restrict__ ctx)
{
    int sT = blockIdx.x, bh = blockIdx.y;
    int b = bh >> 4, h = bh & 15;
    int tid = threadIdx.x;
    int s_l = tid >> 2, dg = (tid & 3) * 16;
    const float* p0 = nump + (((size_t)bh) * (SEQ / 64) + sT) * 4096 + s_l * 64 + dg;
    const float* p1 = nump + (((size_t)BH + bh) * (SEQ / 64) + sT) * 4096 + s_l * 64 + dg;
    int s = sT * 64 + s_l;
    float den = denp[(size_t)bh * SEQ + s] + denp[((size_t)BH + bh) * SEQ + s];
    float inv = 1.0f / fmaxf(den, 1e-12f);
    f16 o[16];
    #pragma unroll
    for (int j4 = 0; j4 < 4; ++j4) {
        float4 a = *(const float4*)(p0 + j4 * 4);
        float4 c = *(const float4*)(p1 + j4 * 4);
        o[j4*4+0] = (f16)((a.x + c.x) * inv);
        o[j4*4+1] = (f16)((a.y + c.y) * inv);
        o[j4*4+2] = (f16)((a.z + c.z) * inv);
        o[j4*4+3] = (f16)((a.w + c.w) * inv);
    }
    f16* dst = ctx + ((size_t)(b * SEQ + s)) * HIDN + h * HD + dg;
    *(f16x8*)dst = *(f16x8*)&o[0];
    *(f16x8*)(dst + 8) = *(f16x8*)&o[8];
}

extern "C" void kernel_launch(void* const* d_in, const int* in_sizes, int n_in,
                              void* d_out, int out_size, void* d_ws, size_t ws_size,
                              hipStream_t stream) {
    const float* x      = (const float*)d_in[0];
    const float* qkv_w  = (const float*)d_in[1];
    const float* qkv_b  = (const float*)d_in[2];
    const float* out_w  = (const float*)d_in[3];
    const float* out_b  = (const float*)d_in[4];
    float* out = (float*)d_out;

    const size_t NTT = (size_t)BH * SEQ * HD;             // 4.19M
    float* qkv = (float*)d_ws;                            // 12.58M f32
    float* nump = qkv;                                    // aliases dead qkv
    float* denp = nump + (size_t)2 * BH * (SEQ/64) * 4096;
    float* colp = denp + (size_t)2 * BH * SEQ;
    float* col = qkv + (size_t)ROWS * 3 * HIDN;           // holds lcl
    f16* xh    = (f16*)(col + (size_t)BH * SEQ);
    f16* wqh   = xh + (size_t)ROWS * HIDN;
    f16* woh   = wqh + (size_t)3 * HIDN * HIDN;
    f16* ctxh  = woh + (size_t)HIDN * HIDN;
    f16* qfp   = ctxh + (size_t)ROWS * HIDN;
    f16* kfp   = qfp + NTT;
    unsigned short* vth = (unsigned short*)(kfp + NTT);

    conv_f16<<<ROWS*HIDN/2048, 256, 0, stream>>>(x, xh);
    conv_f16<<<3*HIDN*HIDN/2048, 256, 0, stream>>>(qkv_w, wqh);
    conv_f16<<<HIDN*HIDN/2048, 256, 0, stream>>>(out_w, woh);

    gemm_nt_f16<<<dim3(ROWS/128, 3*HIDN/128), 256, 0, stream>>>(
        xh, wqh, qkv_b, qkv, ROWS, 3*HIDN, HIDN);
    normalize_qk_f16<<<ROWS*NH/4, 256, 0, stream>>>(qkv, qfp, kfp);
    v_transpose<<<dim3(SEQ/64, BH), 256, 0, stream>>>(qkv, vth);
    col_sum_f16<<<dim3(SEQ/64, BH, 2), 256, 0, stream>>>(qfp, kfp, colp);
    col_finalize<<<BH*SEQ/1024, 256, 0, stream>>>(colp, col);
    attn_f16<<<dim3(SEQ/64, BH, 2), 256, 0, stream>>>(qfp, kfp, vth, col, nump, denp);
    attn_combine<<<dim3(SEQ/64, BH), 256, 0, stream>>>(nump, denp, ctxh);
    gemm_nt_f16<<<dim3(ROWS/128, HIDN/128), 256, 0, stream>>>(
        ctxh, woh, out_b, out, ROWS, HIDN, HIDN);
}

// Round 11
// 328.014 us; speedup vs baseline: 1.7627x; 1.0122x over previous
//
#include <hip/hip_runtime.h>
#include <math.h>

#define NH   16
#define HD   64
#define HIDN 1024
#define NB   2
#define SEQ  2048
#define ROWS (NB*SEQ)   // 4096
#define BH   (NB*NH)    // 32

typedef __attribute__((ext_vector_type(8))) short bf16x8;
typedef __attribute__((ext_vector_type(8))) _Float16 f16x8;
typedef __attribute__((ext_vector_type(4))) float f32x4;
typedef _Float16 f16;

typedef const __attribute__((address_space(1))) void GV;
typedef __attribute__((address_space(3))) void LV;
__device__ __forceinline__ void glds16(const void* g, void* l) {
    __builtin_amdgcn_global_load_lds((GV*)g, (LV*)l, 16, 0, 0);
}

__device__ __forceinline__ unsigned short f2bf(float f) {
    unsigned u = __float_as_uint(f);
    u += 0x7FFF + ((u >> 16) & 1);          // RNE
    return (unsigned short)(u >> 16);
}
__device__ __forceinline__ bf16x8 ldfrag(const unsigned short* p) {
    return *(const bf16x8*)p;
}
__device__ __forceinline__ f16x8 ldfragh(const f16* p) {
    return *(const f16x8*)p;
}
__device__ __forceinline__ f32x4 mfma16(bf16x8 a, bf16x8 b, f32x4 c) {
    return __builtin_amdgcn_mfma_f32_16x16x32_bf16(a, b, c, 0, 0, 0);
}
__device__ __forceinline__ f32x4 mfma16h(f16x8 a, f16x8 b, f32x4 c) {
    return __builtin_amdgcn_mfma_f32_16x16x32_f16(a, b, c, 0, 0, 0);
}

// log2(1 + acos(c)); acos(1-u) ~ sqrt(u)*Q(u), Q = sqrt(2)*P4(u)
__device__ __forceinline__ float log2_1pacos(float c) {
    float u = fmaxf(1.0f - c, 0.0f);
    float s = __builtin_amdgcn_sqrtf(u);
    float p = fmaf(u, 2.68532e-3f, 7.89259e-3f);
    p = fmaf(u, p, 2.6516504e-2f);
    p = fmaf(u, p, 1.1785113e-1f);
    p = fmaf(u, p, 1.4142136f);
    return __builtin_amdgcn_logf(fmaf(s, p, 1.0f));   // log2(1+g)
}

// ---------------- f32 -> f16 convert (n % 8 == 0) ---------------------------
__global__ __launch_bounds__(256)
void conv_f16(const float* __restrict__ src, f16* __restrict__ dst) {
    int i = (blockIdx.x * 256 + threadIdx.x) * 8;
    float4 a = *(const float4*)(src + i);
    float4 b = *(const float4*)(src + i + 4);
    f16x8 o = { (f16)a.x, (f16)a.y, (f16)a.z, (f16)a.w,
                (f16)b.x, (f16)b.y, (f16)b.z, (f16)b.w };
    *(f16x8*)(dst + i) = o;
}

// -------- fp16 MFMA NT GEMM, m97-style global_load_lds staging --------------
// 128x128 tile, BK=32, 2 glls(16B)/operand/wave, frag reads unchanged
__global__ __launch_bounds__(256)
void gemm_nt_f16(const f16* __restrict__ A, const f16* __restrict__ B,
                 const float* __restrict__ bias, float* __restrict__ C,
                 int M, int N, int K)
{
    __shared__ f16 As[128 * 32];
    __shared__ f16 Bs[128 * 32];
    const int tid = threadIdx.x;
    const int lane = tid & 63, w = tid >> 6;
    const int ln = lane & 15, lq = lane >> 4;
    const int wm = (w >> 1) * 64, wn = (w & 1) * 64;
    const int m0 = blockIdx.x * 128, n0 = blockIdx.y * 128;

    // glls mapping: wave w stages rows [32w,32w+32); each glls = 16 rows
    // lane -> row (lane>>2), 16B chunk (lane&3); LDS = base + lane*16 (contig)
    const int grow = lane >> 2;        // 0..15
    const int gcol = (lane & 3) * 8;   // f16 offset
    const f16* Ab = A + (size_t)(m0 + w * 32 + grow) * K + gcol;
    const f16* Bb = B + (size_t)(n0 + w * 32 + grow) * K + gcol;
    f16* Asw = As + (w * 32) * 32;
    f16* Bsw = Bs + (w * 32) * 32;

    f32x4 acc[4][4];
    #pragma unroll
    for (int i = 0; i < 4; ++i)
        #pragma unroll
        for (int j = 0; j < 4; ++j) acc[i][j] = (f32x4){0.f, 0.f, 0.f, 0.f};

    for (int kc = 0; kc < K; kc += 32) {
        __syncthreads();
        #pragma unroll
        for (int i = 0; i < 2; ++i) {
            glds16(Ab + (size_t)(i * 16) * K + kc, Asw + (i * 16) * 32);
            glds16(Bb + (size_t)(i * 16) * K + kc, Bsw + (i * 16) * 32);
        }
        __syncthreads();
        f16x8 af[4], bf[4];
        #pragma unroll
        for (int i = 0; i < 4; ++i)
            af[i] = *(const f16x8*)&As[(wm + i * 16 + ln) * 32 + lq * 8];
        #pragma unroll
        for (int j = 0; j < 4; ++j)
            bf[j] = *(const f16x8*)&Bs[(wn + j * 16 + ln) * 32 + lq * 8];
        #pragma unroll
        for (int i = 0; i < 4; ++i)
            #pragma unroll
            for (int j = 0; j < 4; ++j)
                acc[i][j] = mfma16h(af[i], bf[j], acc[i][j]);
    }

    #pragma unroll
    for (int i = 0; i < 4; ++i) {
        #pragma unroll
        for (int j = 0; j < 4; ++j) {
            int colIdx = n0 + wn + j * 16 + ln;
            float bs = bias[colIdx];
            #pragma unroll
            for (int r = 0; r < 4; ++r) {
                int row = m0 + wm + i * 16 + lq * 4 + r;
                C[(size_t)row * N + colIdx] = acc[i][j][r] + bs;
            }
        }
    }
}

// ------- normalize q,k -> f16; layout [BH][S][D] ----------------------------
__global__ __launch_bounds__(256)
void normalize_qk_f16(const float* __restrict__ qkv,
                      f16* __restrict__ qf, f16* __restrict__ kf)
{
    int w    = blockIdx.x * 4 + (threadIdx.x >> 6);
    int lane = threadIdx.x & 63;
    int n = w >> 4, h = w & 15;
    int b = n >> 11, s = n & 2047;
    const float* base = qkv + (size_t)n * 3 * HIDN + h * HD;
    float q = base[lane], k = base[HIDN + lane];
    float qs = q * q, ks = k * k;
    #pragma unroll
    for (int o = 32; o; o >>= 1) { qs += __shfl_xor(qs, o); ks += __shfl_xor(ks, o); }
    q *= 1.0f / fmaxf(sqrtf(qs), 1e-12f);
    k *= 1.0f / fmaxf(sqrtf(ks), 1e-12f);
    size_t idx = ((size_t)((b * NH + h) * SEQ + s)) * HD + lane;
    qf[idx] = (f16)q;
    kf[idx] = (f16)k;
}

// ------- V: bf16, transpose to [BH][D][S] -----------------------------------
__global__ __launch_bounds__(256)
void v_transpose(const float* __restrict__ qkv, unsigned short* __restrict__ vth)
{
    __shared__ float Ls[64][65];
    int bh = blockIdx.y, s0 = blockIdx.x * 64;
    int b = bh >> 4, h = bh & 15;
    int tid = threadIdx.x;
    #pragma unroll
    for (int i = 0; i < 4; ++i) {
        int idx = tid + i * 256;
        int row = idx >> 4, c4 = (idx & 15) * 4;
        float4 v = *(const float4*)&qkv[((size_t)(b * SEQ + s0 + row)) * 3 * HIDN
                                        + 2 * HIDN + h * HD + c4];
        Ls[row][c4+0] = v.x; Ls[row][c4+1] = v.y; Ls[row][c4+2] = v.z; Ls[row][c4+3] = v.w;
    }
    __syncthreads();
    int d = tid >> 2, sb = (tid & 3) * 16;
    unsigned short hi[16];
    #pragma unroll
    for (int j = 0; j < 16; ++j) hi[j] = f2bf(Ls[sb + j][d]);
    size_t o = ((size_t)bh * HD + d) * SEQ + s0 + sb;
    *(uint4*)&vth[o]     = *(uint4*)&hi[0];
    *(uint4*)&vth[o + 8] = *(uint4*)&hi[8];
}

// KSTR=72 f16 -> 144 B row stride: 16B-aligned (b128-clean), 2-way bank
// aliasing only (free). 68 was 8B-aligned -> misaligned b128, 2.5x regression.
#define KSTR 72

// ------- full col sums (z=1): colp[bh][t] = sum_s w(s,t) --------------------
// grid (SEQ/64, BH) = 1024 blocks = 4/CU: fully-resident single cohort
__global__ __launch_bounds__(256)
void col_sum_f16(const f16* __restrict__ qf, const f16* __restrict__ kf,
                 float* __restrict__ colp)
{
    __shared__ __align__(16) f16 Qs[64 * KSTR];
    int bh = blockIdx.y;
    int tid = threadIdx.x, w = tid >> 6, lane = tid & 63, ln = lane & 15, lq = lane >> 4;
    int m0 = blockIdx.x * 64 + w * 16;
    const f16* qb = qf + (size_t)bh * SEQ * HD;
    const int sr = tid >> 3;          // tile row 0..31
    const int sc = (tid & 7) * 8;     // f16 col offset

    size_t rowK = ((size_t)bh * SEQ + m0 + ln) * HD;
    f16x8 kf0 = ldfragh(kf + rowK + lq * 8), kf1 = ldfragh(kf + rowK + 32 + lq * 8);

    uint4 qa = *(const uint4*)(qb + (size_t)sr * HD + sc);
    uint4 qc = *(const uint4*)(qb + (size_t)(sr + 32) * HD + sc);

    float cacc[4] = {0.f, 0.f, 0.f, 0.f};
    #pragma unroll 1
    for (int st = 0; st < SEQ / 64; ++st) {
        __syncthreads();
        *(uint4*)&Qs[sr * KSTR + sc] = qa;
        *(uint4*)&Qs[(sr + 32) * KSTR + sc] = qc;
        int sn = (st + 1 < SEQ / 64) ? (st + 1) * 64 : 0;
        qa = *(const uint4*)(qb + (size_t)(sn + sr) * HD + sc);
        qc = *(const uint4*)(qb + (size_t)(sn + sr + 32) * HD + sc);
        __syncthreads();
        #pragma unroll
        for (int nt = 0; nt < 4; ++nt) {
            const f16* qp = &Qs[(nt * 16 + ln) * KSTR + lq * 8];
            f32x4 sacc = {0.f, 0.f, 0.f, 0.f};
            sacc = mfma16h(kf0, *(const f16x8*)qp, sacc);
            sacc = mfma16h(kf1, *(const f16x8*)(qp + 32), sacc);
            #pragma unroll
            for (int r = 0; r < 4; ++r)
                cacc[r] += __builtin_amdgcn_exp2f(-65.0f * log2_1pacos(sacc[r]));
        }
    }
    #pragma unroll
    for (int r = 0; r < 4; ++r) {
        float v = cacc[r];
        v += __shfl_xor(v, 1); v += __shfl_xor(v, 2);
        v += __shfl_xor(v, 4); v += __shfl_xor(v, 8);
        if (ln == 0)
            colp[(size_t)bh * SEQ + m0 + lq * 4 + r] = v;
    }
}

// ------- col finalize: lcl = -0.5*log2(c) -----------------------------------
__global__ __launch_bounds__(256)
void col_finalize(const float* __restrict__ colp, float* __restrict__ col)
{
    int i = (blockIdx.x * 256 + threadIdx.x) * 4;
    float4 a = *(const float4*)&colp[i];
    float4 o;
    o.x = -0.5f * __builtin_amdgcn_logf(a.x);
    o.y = -0.5f * __builtin_amdgcn_logf(a.y);
    o.z = -0.5f * __builtin_amdgcn_logf(a.z);
    o.w = -0.5f * __builtin_amdgcn_logf(a.w);
    *(float4*)&col[i] = o;
}

// ------- attention (z=1): full t loop, direct ctx write ---------------------
// score: w = exp2(-65*log2(1+g) + lcl); den via ones-MFMA; W stored RTZ bf16
__global__ __launch_bounds__(256)
void attn_f16(const f16* __restrict__ qf, const f16* __restrict__ kf,
              const unsigned short* __restrict__ vth,
              const float* __restrict__ col, f16* __restrict__ ctx)
{
    __shared__ __align__(16) f16 Ks[64 * KSTR];
    __shared__ __align__(16) unsigned short Vs[64 * KSTR];
    __shared__ __align__(16) unsigned short Ws[4][16 * KSTR];
    __shared__ float lcls[64];
    int bh = blockIdx.y;
    int b = bh >> 4, h = bh & 15;
    int tid = threadIdx.x, w = tid >> 6, lane = tid & 63, ln = lane & 15, lq = lane >> 4;
    int m0 = blockIdx.x * 64 + w * 16;
    unsigned short* ws = Ws[w];

    const f16* kb = kf + (size_t)bh * SEQ * HD;
    const unsigned short* vb = vth + (size_t)bh * HD * SEQ;
    const float* cb = col + (size_t)bh * SEQ;

    const int sr = tid >> 3;
    const int sc = (tid & 7) * 8;

    size_t rowQ = ((size_t)bh * SEQ + m0 + ln) * HD;
    f16x8 qf0 = ldfragh(qf + rowQ + lq * 8), qf1 = ldfragh(qf + rowQ + 32 + lq * 8);

    bf16x8 ones;
    #pragma unroll
    for (int i = 0; i < 8; ++i) ones[i] = (short)0x3F80;  // bf16 1.0

    f32x4 num[4];
    #pragma unroll
    for (int nt = 0; nt < 4; ++nt) num[nt] = (f32x4){0.f, 0.f, 0.f, 0.f};
    f32x4 den = {0.f, 0.f, 0.f, 0.f};

    uint4 ka = *(const uint4*)(kb + (size_t)sr * HD + sc);
    uint4 kc = *(const uint4*)(kb + (size_t)(sr + 32) * HD + sc);
    uint4 va = *(const uint4*)(vb + (size_t)sr * SEQ + sc);
    uint4 vc = *(const uint4*)(vb + (size_t)(sr + 32) * SEQ + sc);
    float clv = (tid < 64) ? cb[tid] : 0.f;

    #pragma unroll 1
    for (int tt = 0; tt < SEQ / 64; ++tt) {
        int t0 = tt * 64;
        __syncthreads();
        *(uint4*)&Ks[sr * KSTR + sc] = ka;
        *(uint4*)&Ks[(sr + 32) * KSTR + sc] = kc;
        *(uint4*)&Vs[sr * KSTR + sc] = va;
        *(uint4*)&Vs[(sr + 32) * KSTR + sc] = vc;
        if (tid < 64) lcls[tid] = clv;
        int tn = (tt + 1 < SEQ / 64) ? (tt + 1) * 64 : 0;
        ka = *(const uint4*)(kb + (size_t)(tn + sr) * HD + sc);
        kc = *(const uint4*)(kb + (size_t)(tn + sr + 32) * HD + sc);
        va = *(const uint4*)(vb + (size_t)sr * SEQ + tn + sc);
        vc = *(const uint4*)(vb + (size_t)(sr + 32) * SEQ + tn + sc);
        clv = (tid < 64) ? cb[tn + tid] : 0.f;
        __syncthreads();

        // QK^T + score -> Ws (per-wave, RTZ bf16)
        #pragma unroll
        for (int nt = 0; nt < 4; ++nt) {
            const f16* kp = &Ks[(nt * 16 + ln) * KSTR + lq * 8];
            f32x4 sacc = {0.f, 0.f, 0.f, 0.f};
            sacc = mfma16h(qf0, *(const f16x8*)kp, sacc);
            sacc = mfma16h(qf1, *(const f16x8*)(kp + 32), sacc);
            float lcl = lcls[nt * 16 + ln];
            #pragma unroll
            for (int r = 0; r < 4; ++r) {
                float l = log2_1pacos(sacc[r]);
                float wv = __builtin_amdgcn_exp2f(fmaf(l, -65.0f, lcl));
                ws[(lq * 4 + r) * KSTR + nt * 16 + ln] =
                    (unsigned short)(__float_as_uint(wv) >> 16);   // RTZ
            }
        }
        // W in A-layout; den += W @ ones; num += W @ V
        bf16x8 wa0 = ldfrag(ws + ln * KSTR + lq * 8);
        bf16x8 wa1 = ldfrag(ws + ln * KSTR + 32 + lq * 8);
        den = mfma16(wa0, ones, den);
        den = mfma16(wa1, ones, den);
        #pragma unroll
        for (int nt = 0; nt < 4; ++nt) {
            const unsigned short* vp = &Vs[(nt * 16 + ln) * KSTR + lq * 8];
            num[nt] = mfma16(wa0, *(const bf16x8*)vp, num[nt]);
            num[nt] = mfma16(wa1, *(const bf16x8*)(vp + 32), num[nt]);
        }
    }

    // epilogue: every lane holds den for its rows (all ln identical)
    #pragma unroll
    for (int r = 0; r < 4; ++r) {
        float inv = 1.0f / fmaxf(den[r], 1e-12f);
        int s = m0 + lq * 4 + r;
        #pragma unroll
        for (int nt = 0; nt < 4; ++nt)
            ctx[((size_t)(b * SEQ + s)) * HIDN + h * HD + nt * 16 + ln] =
                (f16)(num[nt][r] * inv);
    }
}

extern "C" void kernel_launch(void* const* d_in, const int* in_sizes, int n_in,
                              void* d_out, int out_size, void* d_ws, size_t ws_size,
                              hipStream_t stream) {
    const float* x      = (const float*)d_in[0];
    const float* qkv_w  = (const float*)d_in[1];
    const float* qkv_b  = (const float*)d_in[2];
    const float* out_w  = (const float*)d_in[3];
    const float* out_b  = (const float*)d_in[4];
    float* out = (float*)d_out;

    const size_t NTT = (size_t)BH * SEQ * HD;             // 4.19M
    float* qkv = (float*)d_ws;                            // 12.58M f32
    float* colp = qkv;                                    // aliases dead qkv
    float* col = qkv + (size_t)ROWS * 3 * HIDN;           // holds lcl
    f16* xh    = (f16*)(col + (size_t)BH * SEQ);
    f16* wqh   = xh + (size_t)ROWS * HIDN;
    f16* woh   = wqh + (size_t)3 * HIDN * HIDN;
    f16* ctxh  = woh + (size_t)HIDN * HIDN;
    f16* qfp   = ctxh + (size_t)ROWS * HIDN;
    f16* kfp   = qfp + NTT;
    unsigned short* vth = (unsigned short*)(kfp + NTT);

    conv_f16<<<ROWS*HIDN/2048, 256, 0, stream>>>(x, xh);
    conv_f16<<<3*HIDN*HIDN/2048, 256, 0, stream>>>(qkv_w, wqh);
    conv_f16<<<HIDN*HIDN/2048, 256, 0, stream>>>(out_w, woh);

    gemm_nt_f16<<<dim3(ROWS/128, 3*HIDN/128), 256, 0, stream>>>(
        xh, wqh, qkv_b, qkv, ROWS, 3*HIDN, HIDN);
    normalize_qk_f16<<<ROWS*NH/4, 256, 0, stream>>>(qkv, qfp, kfp);
    v_transpose<<<dim3(SEQ/64, BH), 256, 0, stream>>>(qkv, vth);
    col_sum_f16<<<dim3(SEQ/64, BH), 256, 0, stream>>>(qfp, kfp, colp);
    col_finalize<<<BH*SEQ/1024, 256, 0, stream>>>(colp, col);
    attn_f16<<<dim3(SEQ/64, BH), 256, 0, stream>>>(qfp, kfp, vth, col, ctxh);
    gemm_nt_f16<<<dim3(ROWS/128, HIDN/128), 256, 0, stream>>>(
        ctxh, woh, out_b, out, ROWS, HIDN, HIDN);
}